// Round 11
// baseline (187.805 us; speedup 1.0000x reference)
//
#include <hip/hip_runtime.h>

#define H_DIM 2048
#define KEY_DIM 2048
#define CONV_DIM 8192
#define QKVZ_DIM 12288
#define NS_ELEMS 524288
#define NC_ELEMS 24576
#define NPQ 16

typedef float f32x4 __attribute__((ext_vector_type(4)));

__device__ __forceinline__ float silu_f(float x) { return x / (1.f + expf(-x)); }
__device__ __forceinline__ f32x4 ld4(const float* p) {
  return *reinterpret_cast<const f32x4*>(p);
}
__device__ __forceinline__ void st4(float* p, f32x4 v) {
  *reinterpret_cast<f32x4*>(p) = v;
}

// ---------------- K1: qkvz partials = h @ Wq ; ba partials = h @ Wba --------
// R3-proven geometry: blocks 0..767 = 48 col-chunks x 16 row-blocks (256x128);
// blocks 768..783 = ba tiles. Plain launch bounds (no occupancy cap -> no spills).
__global__ __launch_bounds__(256) void k_qkvz(
    const float* __restrict__ hsrc, int hparts,
    const float* __restrict__ Wq, const float* __restrict__ Wba,
    float* __restrict__ qpart, float* __restrict__ bapart)
{
  int bid = blockIdx.x, t = threadIdx.x;
  __shared__ float hs[128];
  __shared__ f32x4 red[256];
  int rb = (bid < 768) ? (bid / 48) * 128 : (bid - 768) * 128;
  if (t < 128) {
    float s = 0.f;
    if (hparts == 1) {
      s = hsrc[rb + t];
    } else {
#pragma unroll
      for (int p = 0; p < 32; ++p) s += hsrc[p * H_DIM + rb + t];
    }
    hs[t] = s;
  }
  __syncthreads();
  if (bid < 768) {
    int p = bid / 48;
    int cb = (bid % 48) * 256;
    int jj = cb + (t & 63) * 4;
    int i0 = (t >> 6) * 32;
    f32x4 acc = {0.f, 0.f, 0.f, 0.f};
    const float* wp = Wq + (size_t)(rb + i0) * QKVZ_DIM + jj;
#pragma unroll 8
    for (int ii = 0; ii < 32; ++ii) {
      float hv = hs[i0 + ii];
      acc += hv * ld4(wp + (size_t)ii * QKVZ_DIM);
    }
    red[t] = acc;
    __syncthreads();
    if (t < 64) {
      f32x4 o = red[t] + red[t + 64] + red[t + 128] + red[t + 192];
      st4(qpart + (size_t)p * QKVZ_DIM + cb + t * 4, o);
    }
  } else {
    int p = bid - 768;
    int col = t & 63;
    int i0 = (t >> 6) * 32;
    float acc = 0.f;
#pragma unroll 8
    for (int ii = 0; ii < 32; ++ii)
      acc += hs[i0 + ii] * Wba[(size_t)(rb + i0 + ii) * 64 + col];
    red[t].x = acc;
    __syncthreads();
    if (t < 64)
      bapart[p * 64 + t] = red[t].x + red[t + 64].x + red[t + 128].x + red[t + 192].x;
  }
}

// ---------------- K2: fused conv + state update + norm + out-GEMV ----------
// blocks 0..511: head hh = bid>>4, col-chunk = bid&15 (128 cols of Wo).
// Each block redundantly computes its head's full state (S slice L2/L3-hot);
// only chunk==0 stores nS. blocks 512..535: nC.
__global__ __launch_bounds__(256, 4) void k_stateout(
    const float* __restrict__ S_in, const float* __restrict__ C_in,
    const float* __restrict__ qpart, const float* __restrict__ bapart,
    const float* __restrict__ cw, const float* __restrict__ dtb,
    const float* __restrict__ Al, const float* __restrict__ nw,
    const float* __restrict__ Wo,
    float* __restrict__ nS, float* __restrict__ nC, float* __restrict__ ypart)
{
  int bid = blockIdx.x, t = threadIdx.x;
  if (bid < 512) {
    int hh = bid >> 4, chunk = bid & 15, kqh = hh >> 1;
    __shared__ float kk[128], qq[128], vvf[128], zz[128], of[128], sc[8];
    auto red16 = [&](int c) -> float {
      float s = 0.f;
#pragma unroll
      for (int p = 0; p < NPQ; ++p) s += qpart[(size_t)p * QKVZ_DIM + c];
      return s;
    };
    auto convval = [&](int c, float last) -> float {
      f32x4 w = ld4(cw + (size_t)c * 4);
      float val = C_in[c] * w.x + C_in[CONV_DIM + c] * w.y +
                  C_in[2 * CONV_DIM + c] * w.z + last * w.w;
      return silu_f(val);
    };
    // phase A: k,q
    if (t < 128) {
      int c = KEY_DIM + kqh * 128 + t;
      kk[t] = convval(c, red16(c));
    } else {
      int u = t - 128;
      int c = kqh * 128 + u;
      qq[u] = convval(c, red16(c));
    }
    __syncthreads();
    // phase B: v, z
    if (t < 128) {
      int c = 2 * KEY_DIM + hh * 128 + t;
      vvf[t] = convval(c, red16(c));
    } else {
      int u = t - 128;
      zz[u] = red16(CONV_DIM + hh * 128 + u);
    }
    __syncthreads();
    // phase C: norms + gate scalars
    if (t < 64) {
      float v = kk[t] * kk[t] + kk[t + 64] * kk[t + 64];
      for (int m = 32; m; m >>= 1) v += __shfl_xor(v, m, 64);
      if (t == 0) sc[0] = v;
    } else if (t < 128) {
      int u = t - 64;
      float v = qq[u] * qq[u] + qq[u + 64] * qq[u + 64];
      for (int m = 32; m; m >>= 1) v += __shfl_xor(v, m, 64);
      if (u == 0) sc[1] = v;
    } else if (t == 128) {
      float bs = 0.f;
#pragma unroll
      for (int p = 0; p < NPQ; ++p) bs += bapart[p * 64 + hh];
      sc[2] = 1.f / (1.f + expf(-bs));
    } else if (t == 129) {
      float as = 0.f;
#pragma unroll
      for (int p = 0; p < NPQ; ++p) as += bapart[p * 64 + 32 + hh];
      float x = as + dtb[hh];
      float sp = (x > 15.f) ? x : log1pf(expf(x));
      sc[3] = expf(-expf(Al[hh]) * sp);
    }
    __syncthreads();
    // phase D: state update, full head (redundant per chunk; only chunk 0 stores)
    {
      float rk = rsqrtf(sc[0] + 1e-6f), rq = rsqrtf(sc[1] + 1e-6f);
      float beta = sc[2], decay = sc[3];
      int grp = t >> 5, lane = t & 31;
      int d0 = lane * 4;
      f32x4 k4 = {kk[d0] * rk, kk[d0 + 1] * rk, kk[d0 + 2] * rk, kk[d0 + 3] * rk};
      f32x4 q4 = {qq[d0] * rq, qq[d0 + 1] * rq, qq[d0 + 2] * rq, qq[d0 + 3] * rq};
#pragma unroll 4
      for (int j = 0; j < 16; ++j) {
        int row = j * 8 + grp;
        size_t idx = ((size_t)(hh * 128 + row)) * 128 + d0;
        f32x4 s = ld4(S_in + idx);
        s *= decay;
        float kv = s.x * k4.x + s.y * k4.y + s.z * k4.z + s.w * k4.w;
        for (int m = 16; m; m >>= 1) kv += __shfl_xor(kv, m, 32);
        float dl = (vvf[row] - kv) * beta;
        f32x4 s1 = s + dl * k4;
        if (chunk == 0) st4(nS + idx, s1);
        float op = s1.x * q4.x + s1.y * q4.y + s1.z * q4.z + s1.w * q4.w;
        for (int m = 16; m; m >>= 1) op += __shfl_xor(op, m, 32);
        if (lane == 0) of[row] = op * 0.088388347648318447f;  // DK^-0.5
      }
    }
    __syncthreads();
    // phase E: RMS denom
    if (t < 64) {
      float v = of[t] * of[t] + of[t + 64] * of[t + 64];
      for (int m = 32; m; m >>= 1) v += __shfl_xor(v, m, 64);
      if (t == 0) sc[4] = v;
    }
    __syncthreads();
    // phase F: normalize + gate
    if (t < 128) {
      float rs = rsqrtf(sc[4] * (1.f / 128.f) + 1e-6f);
      of[t] = of[t] * rs * nw[t] * silu_f(zz[t]);
    }
    __syncthreads();
    // phase G: out-GEMV slice (head rows x 128 cols)
    {
      __shared__ f32x4 red[256];
      int rg = t >> 5, cg = t & 31;
      const float* wp = Wo + (size_t)(hh * 128 + rg * 16) * H_DIM + chunk * 128 + cg * 4;
      f32x4 acc = {0.f, 0.f, 0.f, 0.f};
#pragma unroll
      for (int ii = 0; ii < 16; ++ii)
        acc += of[rg * 16 + ii] * ld4(wp + (size_t)ii * H_DIM);
      red[t] = acc;
      __syncthreads();
      if (t < 32) {
        f32x4 o = red[t] + red[t + 32] + red[t + 64] + red[t + 96] +
                  red[t + 128] + red[t + 160] + red[t + 192] + red[t + 224];
        st4(ypart + (size_t)hh * H_DIM + chunk * 128 + t * 4, o);
      }
    }
  } else {
    // nC: rows 0,1 <- C_in rows 1,2 ; row 2 <- reduced pre-conv mixed (qkvz[0:8192])
    int gt = (bid - 512) * 256 + t;  // float4 index
    if (gt < NC_ELEMS / 4) {
      int c4 = gt * 4;
      int row = c4 >> 13;
      int cc = c4 & (CONV_DIM - 1);
      f32x4 v;
      if (row < 2) {
        v = ld4(C_in + (row + 1) * CONV_DIM + cc);
      } else {
        v = (f32x4){0.f, 0.f, 0.f, 0.f};
#pragma unroll
        for (int p = 0; p < NPQ; ++p)
          v += ld4(qpart + (size_t)p * QKVZ_DIM + cc);
      }
      st4(nC + row * CONV_DIM + cc, v);
    }
  }
}

// ---------------- K3: reduce final y partials -> d_out[0:2048] -------------
__global__ __launch_bounds__(256) void k_final(const float* __restrict__ ypart,
                                               float* __restrict__ dst) {
  int c = blockIdx.x * 256 + threadIdx.x;
  float s = 0.f;
#pragma unroll
  for (int p = 0; p < 32; ++p) s += ypart[p * H_DIM + c];
  dst[c] = s;
}

extern "C" void kernel_launch(void* const* d_in, const int* in_sizes, int n_in,
                              void* d_out, int out_size, void* d_ws, size_t ws_size,
                              hipStream_t stream)
{
  const float* hidden  = (const float*)d_in[0];
  const float* Wq_all  = (const float*)d_in[9];
  const float* Wba_all = (const float*)d_in[10];
  const float* cw_all  = (const float*)d_in[11];
  const float* dtb_all = (const float*)d_in[12];
  const float* Al_all  = (const float*)d_in[13];
  const float* nw_all  = (const float*)d_in[14];
  const float* Wo_all  = (const float*)d_in[15];
  float* out = (float*)d_out;
  float* f   = (float*)d_ws;

  // ws layout — every buffer fully overwritten before read; no zeroing needed
  float* qpart  = f;  f += NPQ * QKVZ_DIM;   // 196608
  float* bapart = f;  f += NPQ * 64;         // 1024
  float* ypart  = f;  f += 32 * H_DIM;       // 65536

  for (int L = 0; L < 4; ++L) {
    const float* hsrc = (L == 0) ? hidden : ypart;
    int hparts        = (L == 0) ? 1 : 32;
    const float* S_in = (const float*)d_in[1 + 2 * L];
    const float* C_in = (const float*)d_in[2 + 2 * L];
    float* nS = out + 2048 + (size_t)L * (NS_ELEMS + NC_ELEMS);
    float* nC = nS + NS_ELEMS;

    k_qkvz<<<784, 256, 0, stream>>>(
        hsrc, hparts,
        Wq_all + (size_t)L * H_DIM * QKVZ_DIM,
        Wba_all + (size_t)L * H_DIM * 64,
        qpart, bapart);

    k_stateout<<<536, 256, 0, stream>>>(
        S_in, C_in, qpart, bapart,
        cw_all + (size_t)L * CONV_DIM * 4,
        dtb_all + L * 32, Al_all + L * 32, nw_all + L * 128,
        Wo_all + (size_t)L * 4096 * H_DIM,
        nS, nC, ypart);
  }
  k_final<<<8, 256, 0, stream>>>(ypart, out);
}

// Round 12
// 147.191 us; speedup vs baseline: 1.2759x; 1.2759x over previous
//
#include <hip/hip_runtime.h>

#define H_DIM 2048
#define KEY_DIM 2048
#define CONV_DIM 8192
#define QKVZ_DIM 12288
#define NS_ELEMS 524288
#define NC_ELEMS 24576
#define NPQ 16

typedef float f32x4 __attribute__((ext_vector_type(4)));

__device__ __forceinline__ float silu_f(float x) { return x / (1.f + expf(-x)); }
__device__ __forceinline__ f32x4 ld4(const float* p) {
  return *reinterpret_cast<const f32x4*>(p);
}
__device__ __forceinline__ void st4(float* p, f32x4 v) {
  *reinterpret_cast<f32x4*>(p) = v;
}

// ---------------- K1: qkvz partials = h @ Wq ; ba partials = h @ Wba --------
// R3/R4-proven: blocks 0..767 = 48 col-chunks x 16 row-blocks (256 cols x 128 rows);
// blocks 768..783 = ba tiles.
__global__ __launch_bounds__(256) void k_qkvz(
    const float* __restrict__ hsrc, int hparts,
    const float* __restrict__ Wq, const float* __restrict__ Wba,
    float* __restrict__ qpart, float* __restrict__ bapart)
{
  int bid = blockIdx.x, t = threadIdx.x;
  __shared__ float hs[128];
  __shared__ f32x4 red[256];
  int rb = (bid < 768) ? (bid / 48) * 128 : (bid - 768) * 128;
  if (t < 128) {
    float s = 0.f;
    if (hparts == 1) {
      s = hsrc[rb + t];
    } else {
#pragma unroll
      for (int p = 0; p < 32; ++p) s += hsrc[p * H_DIM + rb + t];
    }
    hs[t] = s;
  }
  __syncthreads();
  if (bid < 768) {
    int p = bid / 48;
    int cb = (bid % 48) * 256;
    int jj = cb + (t & 63) * 4;
    int i0 = (t >> 6) * 32;
    f32x4 acc = {0.f, 0.f, 0.f, 0.f};
    const float* wp = Wq + (size_t)(rb + i0) * QKVZ_DIM + jj;
#pragma unroll 8
    for (int ii = 0; ii < 32; ++ii) {
      float hv = hs[i0 + ii];
      acc += hv * ld4(wp + (size_t)ii * QKVZ_DIM);
    }
    red[t] = acc;
    __syncthreads();
    if (t < 64) {
      f32x4 o = red[t] + red[t + 64] + red[t + 128] + red[t + 192];
      st4(qpart + (size_t)p * QKVZ_DIM + cb + t * 4, o);
    }
  } else {
    int p = bid - 768;
    int col = t & 63;
    int i0 = (t >> 6) * 32;
    float acc = 0.f;
#pragma unroll 8
    for (int ii = 0; ii < 32; ++ii)
      acc += hs[i0 + ii] * Wba[(size_t)(rb + i0 + ii) * 64 + col];
    red[t].x = acc;
    __syncthreads();
    if (t < 64)
      bapart[p * 64 + t] = red[t].x + red[t + 64].x + red[t + 128].x + red[t + 192].x;
  }
}

// ---------------- K2: conv + state update (8 rows/block) + o_raw; nC --------
// blocks 0..511: hh = bid>>4, sub = bid&15 -> rows sub*8..+8 (S touched once).
// blocks 512..535: nC copy.
__global__ __launch_bounds__(256) void k_state(
    const float* __restrict__ S_in, const float* __restrict__ C_in,
    const float* __restrict__ qpart, const float* __restrict__ bapart,
    const float* __restrict__ cw, const float* __restrict__ dtb,
    const float* __restrict__ Al,
    float* __restrict__ nS, float* __restrict__ nC,
    float* __restrict__ o_raw, float* __restrict__ o2part)
{
  int bid = blockIdx.x, t = threadIdx.x;
  if (bid < 512) {
    int hh = bid >> 4, sub = bid & 15, r0 = sub * 8, kqh = hh >> 1;
    __shared__ float kk[128], qq[128], vv[8], sc[8], o2s[8];
    auto red16 = [&](int c) -> float {
      float s = 0.f;
#pragma unroll
      for (int p = 0; p < NPQ; ++p) s += qpart[(size_t)p * QKVZ_DIM + c];
      return s;
    };
    auto convval = [&](int c, float last) -> float {
      f32x4 w = ld4(cw + (size_t)c * 4);
      float val = C_in[c] * w.x + C_in[CONV_DIM + c] * w.y +
                  C_in[2 * CONV_DIM + c] * w.z + last * w.w;
      return silu_f(val);
    };
    // phase 1: k,q conv (redundant x16 per head; ~33KB L2 reads per block)
    if (t < 128) {
      int c = KEY_DIM + kqh * 128 + t;
      kk[t] = convval(c, red16(c));
    } else {
      int u = t - 128;
      int c = kqh * 128 + u;
      qq[u] = convval(c, red16(c));
    }
    __syncthreads();
    // phase 2: norms + v (8 rows) + gate scalars
    if (t < 64) {
      float v = kk[t] * kk[t] + kk[t + 64] * kk[t + 64];
      for (int m = 32; m; m >>= 1) v += __shfl_xor(v, m, 64);
      if (t == 0) sc[0] = v;
    } else if (t < 128) {
      int u = t - 64;
      float v = qq[u] * qq[u] + qq[u + 64] * qq[u + 64];
      for (int m = 32; m; m >>= 1) v += __shfl_xor(v, m, 64);
      if (u == 0) sc[1] = v;
    } else if (t < 136) {
      int j = t - 128;
      int c = 2 * KEY_DIM + hh * 128 + r0 + j;
      vv[j] = convval(c, red16(c));
    } else if (t == 144) {
      float bs = 0.f;
#pragma unroll
      for (int p = 0; p < NPQ; ++p) bs += bapart[p * 64 + hh];
      sc[2] = 1.f / (1.f + expf(-bs));
    } else if (t == 145) {
      float as = 0.f;
#pragma unroll
      for (int p = 0; p < NPQ; ++p) as += bapart[p * 64 + 32 + hh];
      float x = as + dtb[hh];
      float sp = (x > 15.f) ? x : log1pf(expf(x));
      sc[3] = expf(-expf(Al[hh]) * sp);
    }
    __syncthreads();
    // phase 3: state update, 8 rows (S read/written exactly once grid-wide)
    {
      float rk = rsqrtf(sc[0] + 1e-6f), rq = rsqrtf(sc[1] + 1e-6f);
      float beta = sc[2], decay = sc[3];
      int j = t >> 5, lane = t & 31;
      int d0 = lane * 4;
      f32x4 k4 = {kk[d0] * rk, kk[d0 + 1] * rk, kk[d0 + 2] * rk, kk[d0 + 3] * rk};
      f32x4 q4 = {qq[d0] * rq, qq[d0 + 1] * rq, qq[d0 + 2] * rq, qq[d0 + 3] * rq};
      size_t idx = ((size_t)(hh * 128 + r0 + j)) * 128 + d0;
      f32x4 s = ld4(S_in + idx);
      s *= decay;
      float kv = s.x * k4.x + s.y * k4.y + s.z * k4.z + s.w * k4.w;
      for (int m = 16; m; m >>= 1) kv += __shfl_xor(kv, m, 32);
      float dl = (vv[j] - kv) * beta;
      f32x4 s1 = s + dl * k4;
      st4(nS + idx, s1);
      float op = s1.x * q4.x + s1.y * q4.y + s1.z * q4.z + s1.w * q4.w;
      for (int m = 16; m; m >>= 1) op += __shfl_xor(op, m, 32);
      if (lane == 0) {
        float o = op * 0.088388347648318447f;  // DK^-0.5
        o_raw[hh * 128 + r0 + j] = o;
        o2s[j] = o * o;
      }
    }
    __syncthreads();
    if (t == 0) {
      float s2 = 0.f;
#pragma unroll
      for (int j = 0; j < 8; ++j) s2 += o2s[j];
      o2part[hh * 16 + sub] = s2;
    }
  } else {
    // nC: rows 0,1 <- C_in rows 1,2 ; row 2 <- reduced pre-conv mixed
    int gt = (bid - 512) * 256 + t;  // float4 index
    if (gt < NC_ELEMS / 4) {
      int c4 = gt * 4;
      int row = c4 >> 13;
      int cc = c4 & (CONV_DIM - 1);
      f32x4 v;
      if (row < 2) {
        v = ld4(C_in + (row + 1) * CONV_DIM + cc);
      } else {
        v = (f32x4){0.f, 0.f, 0.f, 0.f};
#pragma unroll
        for (int p = 0; p < NPQ; ++p)
          v += ld4(qpart + (size_t)p * QKVZ_DIM + cc);
      }
      st4(nC + row * CONV_DIM + cc, v);
    }
  }
}

// ---------------- K3: y partials = o_final @ Wo ----------------------------
// 512 blocks: hh = bid>>4, chunk = bid&15 (128 cols); 64KB Wo per block.
__global__ __launch_bounds__(256) void k_gemv_out(
    const float* __restrict__ o_raw, const float* __restrict__ o2part,
    const float* __restrict__ qpart, const float* __restrict__ nw,
    const float* __restrict__ Wo, float* __restrict__ ypart)
{
  int bid = blockIdx.x, t = threadIdx.x;
  int hh = bid >> 4, chunk = bid & 15;
  __shared__ float of[128];
  __shared__ f32x4 red[256];
  if (t < 128) {
    float o2 = 0.f;
#pragma unroll
    for (int s = 0; s < 16; ++s) o2 += o2part[hh * 16 + s];
    float rs = rsqrtf(o2 * (1.f / 128.f) + 1e-6f);
    float z = 0.f;
#pragma unroll
    for (int p = 0; p < NPQ; ++p) z += qpart[(size_t)p * QKVZ_DIM + CONV_DIM + hh * 128 + t];
    of[t] = o_raw[hh * 128 + t] * rs * nw[t] * silu_f(z);
  }
  __syncthreads();
  int rg = t >> 5, cg = t & 31;
  const float* wp = Wo + (size_t)(hh * 128 + rg * 16) * H_DIM + chunk * 128 + cg * 4;
  f32x4 acc = {0.f, 0.f, 0.f, 0.f};
#pragma unroll
  for (int ii = 0; ii < 16; ++ii)
    acc += of[rg * 16 + ii] * ld4(wp + (size_t)ii * H_DIM);
  red[t] = acc;
  __syncthreads();
  if (t < 32) {
    f32x4 o = red[t] + red[t + 32] + red[t + 64] + red[t + 96] +
              red[t + 128] + red[t + 160] + red[t + 192] + red[t + 224];
    st4(ypart + (size_t)hh * H_DIM + chunk * 128 + t * 4, o);
  }
}

// ---------------- K4: reduce final y partials -> d_out[0:2048] -------------
__global__ __launch_bounds__(256) void k_final(const float* __restrict__ ypart,
                                               float* __restrict__ dst) {
  int c = blockIdx.x * 256 + threadIdx.x;
  float s = 0.f;
#pragma unroll
  for (int p = 0; p < 32; ++p) s += ypart[p * H_DIM + c];
  dst[c] = s;
}

extern "C" void kernel_launch(void* const* d_in, const int* in_sizes, int n_in,
                              void* d_out, int out_size, void* d_ws, size_t ws_size,
                              hipStream_t stream)
{
  const float* hidden  = (const float*)d_in[0];
  const float* Wq_all  = (const float*)d_in[9];
  const float* Wba_all = (const float*)d_in[10];
  const float* cw_all  = (const float*)d_in[11];
  const float* dtb_all = (const float*)d_in[12];
  const float* Al_all  = (const float*)d_in[13];
  const float* nw_all  = (const float*)d_in[14];
  const float* Wo_all  = (const float*)d_in[15];
  float* out = (float*)d_out;
  float* f   = (float*)d_ws;

  // ws layout — every buffer fully overwritten before read; no zeroing needed
  float* qpart  = f;  f += NPQ * QKVZ_DIM;   // 196608
  float* bapart = f;  f += NPQ * 64;         // 1024
  float* o2part = f;  f += 32 * 16;          // 512
  float* o_raw  = f;  f += 4096;
  float* ypart  = f;  f += 32 * H_DIM;       // 65536

  for (int L = 0; L < 4; ++L) {
    const float* hsrc = (L == 0) ? hidden : ypart;
    int hparts        = (L == 0) ? 1 : 32;
    const float* S_in = (const float*)d_in[1 + 2 * L];
    const float* C_in = (const float*)d_in[2 + 2 * L];
    float* nS = out + 2048 + (size_t)L * (NS_ELEMS + NC_ELEMS);
    float* nC = nS + NS_ELEMS;

    k_qkvz<<<784, 256, 0, stream>>>(
        hsrc, hparts,
        Wq_all + (size_t)L * H_DIM * QKVZ_DIM,
        Wba_all + (size_t)L * H_DIM * 64,
        qpart, bapart);

    k_state<<<536, 256, 0, stream>>>(
        S_in, C_in, qpart, bapart,
        cw_all + (size_t)L * CONV_DIM * 4,
        dtb_all + L * 32, Al_all + L * 32,
        nS, nC, o_raw, o2part);

    k_gemv_out<<<512, 256, 0, stream>>>(
        o_raw, o2part, qpart, nw_all + L * 128,
        Wo_all + (size_t)L * 4096 * H_DIM, ypart);
  }
  k_final<<<8, 256, 0, stream>>>(ypart, out);
}